// Round 1
// baseline (1013.663 us; speedup 1.0000x reference)
//
#include <hip/hip_runtime.h>
#include <math.h>

#define D 128
#define NB 4      // num bases
#define NR 8      // num relations
#define NLAYER 2
#define EPSV 1e-5f
#define SLOPE 0.2f

// ---------------- block reductions (128 threads = 2 waves) ----------------
__device__ __forceinline__ float block_sum_128(float v, volatile float* scratch) {
#pragma unroll
  for (int off = 32; off > 0; off >>= 1) v += __shfl_xor(v, off);
  __syncthreads();                       // protect scratch from previous use
  if ((threadIdx.x & 63) == 0) scratch[threadIdx.x >> 6] = v;
  __syncthreads();
  return scratch[0] + scratch[1];
}
__device__ __forceinline__ float block_max_128(float v, volatile float* scratch) {
#pragma unroll
  for (int off = 32; off > 0; off >>= 1) v = fmaxf(v, __shfl_xor(v, off));
  __syncthreads();
  if ((threadIdx.x & 63) == 0) scratch[threadIdx.x >> 6] = v;
  __syncthreads();
  return fmaxf(scratch[0], scratch[1]);
}

// ---------------- CSR build ----------------
__global__ void hist_kernel(const int* __restrict__ dst, int* __restrict__ deg, int E) {
  int e = blockIdx.x * 256 + threadIdx.x;
  if (e < E) atomicAdd(&deg[dst[e]], 1);
}

__global__ void __launch_bounds__(1024) scan_kernel(const int* __restrict__ deg,
                                                    int* __restrict__ offs,
                                                    int* __restrict__ cur, int n) {
  __shared__ int wsums[16];
  const int tid = threadIdx.x, lane = tid & 63, wid = tid >> 6;
  int carry = 0;
  for (int base = 0; base < n + 1023; base += 1024) {
    int i = base + tid;
    int v = (i < n) ? deg[i] : 0;
    int x = v;
#pragma unroll
    for (int off = 1; off < 64; off <<= 1) {
      int yv = __shfl_up(x, off);
      if (lane >= off) x += yv;
    }
    if (lane == 63) wsums[wid] = x;
    __syncthreads();
    if (wid == 0) {
      int ws = (lane < 16) ? wsums[lane] : 0;
#pragma unroll
      for (int off = 1; off < 16; off <<= 1) {
        int yv = __shfl_up(ws, off);
        if (lane >= off) ws += yv;
      }
      if (lane < 16) wsums[lane] = ws;
    }
    __syncthreads();
    int prefix = (wid > 0) ? wsums[wid - 1] : 0;
    int excl = carry + prefix + x - v;
    if (i < n) { offs[i] = excl; cur[i] = excl; }
    int btot = wsums[15];
    __syncthreads();                     // before next chunk overwrites wsums
    carry += btot;
  }
  if (tid == 0) offs[n] = carry;
}

__global__ void scatter_kernel(const int* __restrict__ src, const int* __restrict__ dst,
                               const int* __restrict__ et, int* __restrict__ cur,
                               unsigned* __restrict__ csr, int E) {
  int e = blockIdx.x * 256 + threadIdx.x;
  if (e < E) {
    int d = dst[e];
    int pos = atomicAdd(&cur[d], 1);
    csr[pos] = (unsigned)src[e] | ((unsigned)et[e] << 16);
  }
}

// ---------------- GEMM: [N,128] @ [128, 640] -> y[N,512] (4 bases), xr[N,128] ----------------
// 64 nodes x 64 cols per block, 256 threads, 4x4 microtile, K split in 2 passes of 64.
__global__ void __launch_bounds__(256) gemm_kernel(const float* __restrict__ x,
                                                   const float* __restrict__ basis_l,
                                                   const float* __restrict__ root_l,
                                                   float* __restrict__ y,
                                                   float* __restrict__ xr, int n_nodes) {
  __shared__ float sA[64][68];   // [row][k] padded: ty-stride 272 -> 2-way bank (free)
  __shared__ float sW[64][64];   // [k][col]
  const int tid = threadIdx.x;
  const int bm = blockIdx.x, bn = blockIdx.y;
  const int row0 = bm * 64;
  const float* wptr = (bn < 8) ? (basis_l + (bn >> 1) * (D * D) + (bn & 1) * 64)
                               : (root_l + (bn - 8) * 64);
  const int tx = tid & 15, ty = tid >> 4;
  float acc[4][4] = {};
  for (int kt = 0; kt < 2; ++kt) {
    __syncthreads();
    // load A tile: 64 rows x 64 k (cols kt*64..): 1024 float4 / 256 thr = 4 each
#pragma unroll
    for (int p = 0; p < 4; ++p) {
      int idx = p * 256 + tid;
      int r = idx >> 4, c4 = idx & 15;
      float4 v = make_float4(0.f, 0.f, 0.f, 0.f);
      int gr = row0 + r;
      if (gr < n_nodes) v = *(const float4*)(x + (size_t)gr * D + kt * 64 + c4 * 4);
      *(float4*)(&sA[r][c4 * 4]) = v;
    }
    // load W tile: 64 k x 64 cols
#pragma unroll
    for (int p = 0; p < 4; ++p) {
      int idx = p * 256 + tid;
      int k = idx >> 4, c4 = idx & 15;
      float4 v = *(const float4*)(wptr + (size_t)(kt * 64 + k) * D + c4 * 4);
      *(float4*)(&sW[k][c4 * 4]) = v;
    }
    __syncthreads();
#pragma unroll 8
    for (int k = 0; k < 64; ++k) {
      float a0 = sA[ty * 4 + 0][k], a1 = sA[ty * 4 + 1][k];
      float a2 = sA[ty * 4 + 2][k], a3 = sA[ty * 4 + 3][k];
      float4 b = *(const float4*)(&sW[k][tx * 4]);
      acc[0][0] = fmaf(a0, b.x, acc[0][0]); acc[0][1] = fmaf(a0, b.y, acc[0][1]);
      acc[0][2] = fmaf(a0, b.z, acc[0][2]); acc[0][3] = fmaf(a0, b.w, acc[0][3]);
      acc[1][0] = fmaf(a1, b.x, acc[1][0]); acc[1][1] = fmaf(a1, b.y, acc[1][1]);
      acc[1][2] = fmaf(a1, b.z, acc[1][2]); acc[1][3] = fmaf(a1, b.w, acc[1][3]);
      acc[2][0] = fmaf(a2, b.x, acc[2][0]); acc[2][1] = fmaf(a2, b.y, acc[2][1]);
      acc[2][2] = fmaf(a2, b.z, acc[2][2]); acc[2][3] = fmaf(a2, b.w, acc[2][3]);
      acc[3][0] = fmaf(a3, b.x, acc[3][0]); acc[3][1] = fmaf(a3, b.y, acc[3][1]);
      acc[3][2] = fmaf(a3, b.z, acc[3][2]); acc[3][3] = fmaf(a3, b.w, acc[3][3]);
    }
  }
#pragma unroll
  for (int i = 0; i < 4; ++i) {
    int gr = row0 + ty * 4 + i;
    if (gr >= n_nodes) continue;
    int col0 = bn * 64 + tx * 4;
    float4 v = make_float4(acc[i][0], acc[i][1], acc[i][2], acc[i][3]);
    if (bn < 8) *(float4*)(y + (size_t)gr * (NB * D) + col0) = v;
    else        *(float4*)(xr + (size_t)gr * D + (col0 - 8 * 64)) = v;
  }
}

// ---------------- per-node attention scalars ----------------
__global__ void __launch_bounds__(128) a_kernel(const float* __restrict__ y,
                                                const float* __restrict__ xr,
                                                const float* __restrict__ att_l,
                                                float* __restrict__ ai,
                                                float* __restrict__ ajb) {
  __shared__ float scratch[2];
  const int n = blockIdx.x, t = threadIdx.x;
  const float att1 = att_l[t], att2 = att_l[D + t];
  const float* yr = y + (size_t)n * (NB * D);
  float s0 = block_sum_128(yr[t] * att2, scratch);
  float s1 = block_sum_128(yr[D + t] * att2, scratch);
  float s2 = block_sum_128(yr[2 * D + t] * att2, scratch);
  float s3 = block_sum_128(yr[3 * D + t] * att2, scratch);
  float sr = block_sum_128(xr[(size_t)n * D + t] * att1, scratch);
  if (t == 0) {
    ajb[n * 4 + 0] = s0; ajb[n * 4 + 1] = s1;
    ajb[n * 4 + 2] = s2; ajb[n * 4 + 3] = s3;
    ai[n] = sr;
  }
}

// ---------------- fused per-node: softmax(attn) + aggregate + LN + tanh ----------------
__global__ void __launch_bounds__(128) node_kernel(
    const float* __restrict__ y, const float* __restrict__ xr,
    const float* __restrict__ ai, const float* __restrict__ ajb,
    const int* __restrict__ offs, const unsigned* __restrict__ csr,
    const float* __restrict__ attr_l, const float* __restrict__ bias_l,
    const float* __restrict__ lnw_l, const float* __restrict__ lnb_l,
    float* __restrict__ st, float* __restrict__ xfinal) {
  __shared__ float s_c[NR * NB];
  __shared__ float s_ex[128];
  __shared__ unsigned s_pk[128];
  __shared__ float scratch[2];
  const int n = blockIdx.x, t = threadIdx.x;
  if (t < NR * NB) s_c[t] = attr_l[t];
  const int b0 = offs[n], b1 = offs[n + 1];
  const float ain = ai[n];
  __syncthreads();
  float m = -INFINITY, ssum = 0.f, aggr = 0.f;
  for (int cb = b0; cb < b1; cb += 128) {
    int cnt = min(128, b1 - cb);
    float alpha = -INFINITY;
    unsigned pk = 0;
    if (t < cnt) {
      pk = csr[cb + t];
      unsigned sn = pk & 0xFFFFu, rt = pk >> 16;
      float4 aj = *(const float4*)(ajb + (size_t)sn * 4);
      float a = ain + s_c[rt * 4 + 0] * aj.x + s_c[rt * 4 + 1] * aj.y +
                s_c[rt * 4 + 2] * aj.z + s_c[rt * 4 + 3] * aj.w;
      alpha = a > 0.f ? a : SLOPE * a;
    }
    s_pk[t] = pk;
    float cmax = block_max_128(alpha, scratch);
    float nm = fmaxf(m, cmax);                    // finite: cnt >= 1
    float ex = (t < cnt) ? __expf(alpha - nm) : 0.f;
    s_ex[t] = ex;
    float csum = block_sum_128(ex, scratch);      // also publishes s_ex/s_pk
    float f = __expf(m - nm);                     // first chunk: exp(-inf)=0, s=aggr=0 anyway
    ssum = ssum * f + csum;
    aggr *= f;
    m = nm;
    for (int j = 0; j < cnt; ++j) {
      unsigned pj = s_pk[j];
      float w = s_ex[j];
      unsigned sn = pj & 0xFFFFu, rt = pj >> 16;
      const float* yb = y + (size_t)sn * (NB * D) + t;
      float xj = s_c[rt * 4 + 0] * yb[0] + s_c[rt * 4 + 1] * yb[D] +
                 s_c[rt * 4 + 2] * yb[2 * D] + s_c[rt * 4 + 3] * yb[3 * D];
      aggr = fmaf(w, xj, aggr);
    }
    __syncthreads();                              // protect s_pk/s_ex for next chunk
  }
  float outv = aggr / (ssum + 1e-16f) + xr[(size_t)n * D + t] + bias_l[t];
  float mu = block_sum_128(outv, scratch) * (1.0f / D);
  float dd = outv - mu;
  float var = block_sum_128(dd * dd, scratch) * (1.0f / D);
  float nv = dd * rsqrtf(var + EPSV) * lnw_l[t] + lnb_l[t];
  float val = tanhf(nv);
  st[(size_t)n * D + t] = val;
  if (xfinal) xfinal[(size_t)n * D + t] = val;
}

// ---------------- launch ----------------
extern "C" void kernel_launch(void* const* d_in, const int* in_sizes, int n_in,
                              void* d_out, int out_size, void* d_ws, size_t ws_size,
                              hipStream_t stream) {
  const float* x0    = (const float*)d_in[0];
  const int*   ei    = (const int*)d_in[1];
  const int*   etype = (const int*)d_in[2];
  const float* basis = (const float*)d_in[3];
  const float* att_r = (const float*)d_in[4];
  const float* att   = (const float*)d_in[5];
  const float* root  = (const float*)d_in[6];
  const float* bias  = (const float*)d_in[7];
  const float* lnw   = (const float*)d_in[8];
  const float* lnb   = (const float*)d_in[9];
  float* out = (float*)d_out;
  const int N = in_sizes[0] / D;
  const int E = in_sizes[2];

  char* p = (char*)d_ws;
  auto alloc = [&](size_t bytes) { void* r = (void*)p; p += (bytes + 255) & ~(size_t)255; return r; };
  float*    y    = (float*)alloc((size_t)N * NB * D * 4);
  float*    xr   = (float*)alloc((size_t)N * D * 4);
  float*    ai   = (float*)alloc((size_t)N * 4);
  float*    ajb  = (float*)alloc((size_t)N * 4 * 4);
  int*      deg  = (int*)alloc((size_t)N * 4);
  int*      offs = (int*)alloc((size_t)(N + 1) * 4);
  int*      cur  = (int*)alloc((size_t)N * 4);
  unsigned* csr  = (unsigned*)alloc((size_t)E * 4);

  const int* srcp = ei;
  const int* dstp = ei + E;

  // CSR by dst (edge order within a segment differs from ref: sums/max are order-insensitive)
  hipMemsetAsync(deg, 0, (size_t)N * 4, stream);
  hist_kernel<<<(E + 255) / 256, 256, 0, stream>>>(dstp, deg, E);
  scan_kernel<<<1, 1024, 0, stream>>>(deg, offs, cur, N);
  scatter_kernel<<<(E + 255) / 256, 256, 0, stream>>>(srcp, dstp, etype, cur, csr, E);

  float* states = out + (size_t)N * D;  // [L, N, D]; out[0:N*D] = final x
  const float* xin = x0;
  for (int l = 0; l < NLAYER; ++l) {
    gemm_kernel<<<dim3((N + 63) / 64, 10), 256, 0, stream>>>(
        xin, basis + (size_t)l * NB * D * D, root + (size_t)l * D * D, y, xr, N);
    a_kernel<<<N, 128, 0, stream>>>(y, xr, att + (size_t)l * 2 * D, ai, ajb);
    float* st = states + (size_t)l * N * D;
    node_kernel<<<N, 128, 0, stream>>>(y, xr, ai, ajb, offs, csr,
                                       att_r + (size_t)l * NR * NB, bias + (size_t)l * D,
                                       lnw + (size_t)l * D, lnb + (size_t)l * D,
                                       st, (l == NLAYER - 1) ? out : nullptr);
    xin = st;
  }
}

// Round 2
// 722.037 us; speedup vs baseline: 1.4039x; 1.4039x over previous
//
#include <hip/hip_runtime.h>
#include <math.h>

#define D 128
#define NB 4      // num bases
#define NR 8      // num relations
#define NLAYER 2
#define EPSV 1e-5f
#define SLOPE 0.2f

typedef __attribute__((ext_vector_type(8))) short short8;   // 8 bf16 = 4 VGPRs
typedef __attribute__((ext_vector_type(4))) float f32x4;

__device__ __forceinline__ unsigned short f2bf(float f) {
  unsigned u = __float_as_uint(f);
  u += 0x7FFF + ((u >> 16) & 1);          // round-to-nearest-even
  return (unsigned short)(u >> 16);
}

// ---------------- block reductions (128 threads = 2 waves) ----------------
__device__ __forceinline__ float block_sum_128(float v, volatile float* scratch) {
#pragma unroll
  for (int off = 32; off > 0; off >>= 1) v += __shfl_xor(v, off);
  __syncthreads();
  if ((threadIdx.x & 63) == 0) scratch[threadIdx.x >> 6] = v;
  __syncthreads();
  return scratch[0] + scratch[1];
}
__device__ __forceinline__ float block_max_128(float v, volatile float* scratch) {
#pragma unroll
  for (int off = 32; off > 0; off >>= 1) v = fmaxf(v, __shfl_xor(v, off));
  __syncthreads();
  if ((threadIdx.x & 63) == 0) scratch[threadIdx.x >> 6] = v;
  __syncthreads();
  return fmaxf(scratch[0], scratch[1]);
}

// ---------------- CSR build ----------------
__global__ void hist_kernel(const int* __restrict__ dst, int* __restrict__ deg, int E) {
  int e = blockIdx.x * 256 + threadIdx.x;
  if (e < E) atomicAdd(&deg[dst[e]], 1);
}

__global__ void __launch_bounds__(1024) scan_kernel(const int* __restrict__ deg,
                                                    int* __restrict__ offs,
                                                    int* __restrict__ cur, int n) {
  __shared__ int wsums[16];
  const int tid = threadIdx.x, lane = tid & 63, wid = tid >> 6;
  int carry = 0;
  for (int base = 0; base < n + 1023; base += 1024) {
    int i = base + tid;
    int v = (i < n) ? deg[i] : 0;
    int x = v;
#pragma unroll
    for (int off = 1; off < 64; off <<= 1) {
      int yv = __shfl_up(x, off);
      if (lane >= off) x += yv;
    }
    if (lane == 63) wsums[wid] = x;
    __syncthreads();
    if (wid == 0) {
      int ws = (lane < 16) ? wsums[lane] : 0;
#pragma unroll
      for (int off = 1; off < 16; off <<= 1) {
        int yv = __shfl_up(ws, off);
        if (lane >= off) ws += yv;
      }
      if (lane < 16) wsums[lane] = ws;
    }
    __syncthreads();
    int prefix = (wid > 0) ? wsums[wid - 1] : 0;
    int excl = carry + prefix + x - v;
    if (i < n) { offs[i] = excl; cur[i] = excl; }
    int btot = wsums[15];
    __syncthreads();
    carry += btot;
  }
  if (tid == 0) offs[n] = carry;
}

__global__ void scatter_kernel(const int* __restrict__ src, const int* __restrict__ dst,
                               const int* __restrict__ et, int* __restrict__ cur,
                               unsigned* __restrict__ csr, int E) {
  int e = blockIdx.x * 256 + threadIdx.x;
  if (e < E) {
    int d = dst[e];
    int pos = atomicAdd(&cur[d], 1);
    csr[pos] = (unsigned)src[e] | ((unsigned)et[e] << 16);
  }
}

// ---------------- per-layer weight prep ----------------
// BT[o][k] = bf16(basis[b][i][o]), k = b*128+i  ->  [128][512] bf16 (k contiguous)
__global__ void bt_kernel(const float* __restrict__ basis_l, unsigned short* __restrict__ BT) {
  int idx = blockIdx.x * 256 + threadIdx.x;       // 65536
  int o = idx & 127, k = idx >> 7;
  BT[(size_t)o * 512 + k] = f2bf(basis_l[(size_t)k * 128 + o]);
}
// bv[b][i] = sum_o basis[b][i][o] * att2[o]
__global__ void bv_kernel(const float* __restrict__ basis_l, const float* __restrict__ att_l,
                          float* __restrict__ bv) {
  int tid = threadIdx.x;                          // 512
  int b = tid >> 7, i = tid & 127;
  const float* bp = basis_l + (size_t)b * (D * D) + (size_t)i * D;
  float s = 0.f;
#pragma unroll 8
  for (int o = 0; o < D; ++o) s = fmaf(bp[o], att_l[D + o], s);
  bv[tid] = s;
}

// ---------------- xr GEMM: [N,128] @ root[128,128] -> xr ----------------
__global__ void __launch_bounds__(256) gemm_xr(const float* __restrict__ x,
                                               const float* __restrict__ root_l,
                                               float* __restrict__ xr, int n_nodes) {
  __shared__ float sA[64][68];
  __shared__ float sW[64][64];
  const int tid = threadIdx.x;
  const int row0 = blockIdx.x * 64, bn = blockIdx.y;
  const float* wptr = root_l + bn * 64;
  const int tx = tid & 15, ty = tid >> 4;
  float acc[4][4] = {};
  for (int kt = 0; kt < 2; ++kt) {
    __syncthreads();
#pragma unroll
    for (int p = 0; p < 4; ++p) {
      int idx = p * 256 + tid;
      int r = idx >> 4, c4 = idx & 15;
      float4 v = make_float4(0.f, 0.f, 0.f, 0.f);
      int gr = row0 + r;
      if (gr < n_nodes) v = *(const float4*)(x + (size_t)gr * D + kt * 64 + c4 * 4);
      *(float4*)(&sA[r][c4 * 4]) = v;
    }
#pragma unroll
    for (int p = 0; p < 4; ++p) {
      int idx = p * 256 + tid;
      int k = idx >> 4, c4 = idx & 15;
      float4 v = *(const float4*)(wptr + (size_t)(kt * 64 + k) * D + c4 * 4);
      *(float4*)(&sW[k][c4 * 4]) = v;
    }
    __syncthreads();
#pragma unroll 8
    for (int k = 0; k < 64; ++k) {
      float a0 = sA[ty * 4 + 0][k], a1 = sA[ty * 4 + 1][k];
      float a2 = sA[ty * 4 + 2][k], a3 = sA[ty * 4 + 3][k];
      float4 b = *(const float4*)(&sW[k][tx * 4]);
      acc[0][0] = fmaf(a0, b.x, acc[0][0]); acc[0][1] = fmaf(a0, b.y, acc[0][1]);
      acc[0][2] = fmaf(a0, b.z, acc[0][2]); acc[0][3] = fmaf(a0, b.w, acc[0][3]);
      acc[1][0] = fmaf(a1, b.x, acc[1][0]); acc[1][1] = fmaf(a1, b.y, acc[1][1]);
      acc[1][2] = fmaf(a1, b.z, acc[1][2]); acc[1][3] = fmaf(a1, b.w, acc[1][3]);
      acc[2][0] = fmaf(a2, b.x, acc[2][0]); acc[2][1] = fmaf(a2, b.y, acc[2][1]);
      acc[2][2] = fmaf(a2, b.z, acc[2][2]); acc[2][3] = fmaf(a2, b.w, acc[2][3]);
      acc[3][0] = fmaf(a3, b.x, acc[3][0]); acc[3][1] = fmaf(a3, b.y, acc[3][1]);
      acc[3][2] = fmaf(a3, b.z, acc[3][2]); acc[3][3] = fmaf(a3, b.w, acc[3][3]);
    }
  }
#pragma unroll
  for (int i = 0; i < 4; ++i) {
    int gr = row0 + ty * 4 + i;
    if (gr >= n_nodes) continue;
    float4 v = make_float4(acc[i][0], acc[i][1], acc[i][2], acc[i][3]);
    *(float4*)(xr + (size_t)gr * D + bn * 64 + tx * 4) = v;
  }
}

// ---------------- per-node attention scalars: ai = xr.att1, ajb[b] = x.bv[b] ----------------
__global__ void __launch_bounds__(128) a2_kernel(const float* __restrict__ x,
                                                 const float* __restrict__ xr,
                                                 const float* __restrict__ att_l,
                                                 const float* __restrict__ bv,
                                                 float* __restrict__ ai,
                                                 float* __restrict__ ajb) {
  __shared__ float scratch[2];
  const int n = blockIdx.x, t = threadIdx.x;
  float xv = x[(size_t)n * D + t];
  float s0 = block_sum_128(xv * bv[t], scratch);
  float s1 = block_sum_128(xv * bv[D + t], scratch);
  float s2 = block_sum_128(xv * bv[2 * D + t], scratch);
  float s3 = block_sum_128(xv * bv[3 * D + t], scratch);
  float sr = block_sum_128(xr[(size_t)n * D + t] * att_l[t], scratch);
  if (t == 0) {
    ajb[n * 4 + 0] = s0; ajb[n * 4 + 1] = s1;
    ajb[n * 4 + 2] = s2; ajb[n * 4 + 3] = s3;
    ai[n] = sr;
  }
}

// ---------------- flash softmax + x-space scatter: g[n,b,:] = sum_e alpha*c[et,b]*x[src] ----
__global__ void __launch_bounds__(128) node_flash(
    const float* __restrict__ x, const float* __restrict__ ai, const float* __restrict__ ajb,
    const int* __restrict__ offs, const unsigned* __restrict__ csr,
    const float* __restrict__ attr_l, unsigned short* __restrict__ g) {
  __shared__ float s_c[NR * NB];
  __shared__ float s_wc[128][4];
  __shared__ float s_ex[128];
  __shared__ unsigned s_pk[128];
  __shared__ float scratch[2];
  const int n = blockIdx.x, t = threadIdx.x;
  if (t < NR * NB) s_c[t] = attr_l[t];
  const int b0 = offs[n], b1 = offs[n + 1];
  const float ain = ai[n];
  __syncthreads();
  float m = -INFINITY, ssum = 0.f;
  float a0 = 0.f, a1 = 0.f, a2 = 0.f, a3 = 0.f;
  for (int cb = b0; cb < b1; cb += 128) {
    int cnt = min(128, b1 - cb);
    float alpha = -INFINITY;
    unsigned pk = 0, rt = 0;
    if (t < cnt) {
      pk = csr[cb + t];
      unsigned sn = pk & 0xFFFFu; rt = pk >> 16;
      float4 aj = *(const float4*)(ajb + (size_t)sn * 4);
      float a = ain + s_c[rt * 4 + 0] * aj.x + s_c[rt * 4 + 1] * aj.y +
                s_c[rt * 4 + 2] * aj.z + s_c[rt * 4 + 3] * aj.w;
      alpha = a > 0.f ? a : SLOPE * a;
    }
    s_pk[t] = pk;
    float cmax = block_max_128(alpha, scratch);
    float nm = fmaxf(m, cmax);
    float ex = (t < cnt) ? __expf(alpha - nm) : 0.f;
    s_ex[t] = ex;
    s_wc[t][0] = ex * s_c[rt * 4 + 0]; s_wc[t][1] = ex * s_c[rt * 4 + 1];
    s_wc[t][2] = ex * s_c[rt * 4 + 2]; s_wc[t][3] = ex * s_c[rt * 4 + 3];
    float csum = block_sum_128(ex, scratch);   // barrier publishes s_ex/s_pk/s_wc
    float f = __expf(m - nm);                  // first chunk: 0, accs are 0
    ssum = ssum * f + csum;
    a0 *= f; a1 *= f; a2 *= f; a3 *= f;
    m = nm;
    for (int j = 0; j < cnt; ++j) {
      unsigned sn = s_pk[j] & 0xFFFFu;
      float xv = x[(size_t)sn * D + t];
      a0 = fmaf(s_wc[j][0], xv, a0);
      a1 = fmaf(s_wc[j][1], xv, a1);
      a2 = fmaf(s_wc[j][2], xv, a2);
      a3 = fmaf(s_wc[j][3], xv, a3);
    }
    __syncthreads();
  }
  float inv = 1.f / (ssum + 1e-16f);
  unsigned short* gp = g + (size_t)n * (NB * D);
  gp[t]         = f2bf(a0 * inv);
  gp[D + t]     = f2bf(a1 * inv);
  gp[2 * D + t] = f2bf(a2 * inv);
  gp[3 * D + t] = f2bf(a3 * inv);
}

// ---------------- MFMA GEMM: out = tanh(LN(g[N,512]@Bflat[512,128] + xr + bias)) ----------
// block = 256 thr = 4 waves; wave w: rows blk*64+w*16..+15, all 128 cols as 8 col-tiles.
// A frag: A[m=lane&15][k=quad*8+j]; B frag: B[k=quad*8+j][n=lane&15] (BT is [col][k]);
// C/D: col=lane&15, row=quad*4+reg.  [layouts per m89/m120-verified mapping]
__global__ void __launch_bounds__(256) gemm2_kernel(
    const unsigned short* __restrict__ g, const unsigned short* __restrict__ BT,
    const float* __restrict__ xr, const float* __restrict__ bias_l,
    const float* __restrict__ lnw_l, const float* __restrict__ lnb_l,
    float* __restrict__ st, float* __restrict__ xfinal, int n_nodes) {
  const int tid = threadIdx.x;
  const int wv = tid >> 6, lane = tid & 63;
  const int l15 = lane & 15, quad = lane >> 4;
  const int rowb = blockIdx.x * 64 + wv * 16;
  const int arow = rowb + l15;                 // < Npad by construction
  f32x4 acc[8];
  const f32x4 zero = {0.f, 0.f, 0.f, 0.f};
#pragma unroll
  for (int ct = 0; ct < 8; ++ct) acc[ct] = zero;
  const short8* ga = (const short8*)(g + (size_t)arow * 512 + quad * 8);
#pragma unroll
  for (int kc = 0; kc < 16; ++kc) {
    short8 a = ga[kc * 4];                     // stride 32 bf16 per chunk
#pragma unroll
    for (int ct = 0; ct < 8; ++ct) {
      const short8* gb = (const short8*)(BT + (size_t)(ct * 16 + l15) * 512 + kc * 32 + quad * 8);
      acc[ct] = __builtin_amdgcn_mfma_f32_16x16x32_bf16(a, *gb, acc[ct], 0, 0, 0);
    }
  }
  // epilogue: + xr + bias, LayerNorm over 128 cols, tanh
  const int r0 = rowb + quad * 4;
  float bia[8], lw[8], lb[8];
#pragma unroll
  for (int ct = 0; ct < 8; ++ct) {
    int col = ct * 16 + l15;
    bia[ct] = bias_l[col]; lw[ct] = lnw_l[col]; lb[ct] = lnb_l[col];
  }
  float vsum[4] = {0.f, 0.f, 0.f, 0.f}, vsq[4] = {0.f, 0.f, 0.f, 0.f};
#pragma unroll
  for (int ct = 0; ct < 8; ++ct) {
#pragma unroll
    for (int r = 0; r < 4; ++r) {
      int row = r0 + r;
      float xv = (row < n_nodes) ? xr[(size_t)row * D + ct * 16 + l15] : 0.f;
      float v = acc[ct][r] + xv + bia[ct];
      acc[ct][r] = v;
      vsum[r] += v; vsq[r] += v * v;
    }
  }
#pragma unroll
  for (int r = 0; r < 4; ++r) {
#pragma unroll
    for (int off = 1; off < 16; off <<= 1) {
      vsum[r] += __shfl_xor(vsum[r], off);
      vsq[r]  += __shfl_xor(vsq[r], off);
    }
  }
  float mu[4], rs[4];
#pragma unroll
  for (int r = 0; r < 4; ++r) {
    mu[r] = vsum[r] * (1.0f / D);
    float var = vsq[r] * (1.0f / D) - mu[r] * mu[r];
    rs[r] = rsqrtf(var + EPSV);
  }
#pragma unroll
  for (int ct = 0; ct < 8; ++ct) {
#pragma unroll
    for (int r = 0; r < 4; ++r) {
      int row = r0 + r;
      if (row >= n_nodes) continue;
      float nv = (acc[ct][r] - mu[r]) * rs[r] * lw[ct] + lb[ct];
      float val = tanhf(nv);
      st[(size_t)row * D + ct * 16 + l15] = val;
      if (xfinal) xfinal[(size_t)row * D + ct * 16 + l15] = val;
    }
  }
}

// ---------------- launch ----------------
extern "C" void kernel_launch(void* const* d_in, const int* in_sizes, int n_in,
                              void* d_out, int out_size, void* d_ws, size_t ws_size,
                              hipStream_t stream) {
  const float* x0    = (const float*)d_in[0];
  const int*   ei    = (const int*)d_in[1];
  const int*   etype = (const int*)d_in[2];
  const float* basis = (const float*)d_in[3];
  const float* att_r = (const float*)d_in[4];
  const float* att   = (const float*)d_in[5];
  const float* root  = (const float*)d_in[6];
  const float* bias  = (const float*)d_in[7];
  const float* lnw   = (const float*)d_in[8];
  const float* lnb   = (const float*)d_in[9];
  float* out = (float*)d_out;
  const int N = in_sizes[0] / D;
  const int E = in_sizes[2];
  const int Npad = ((N + 63) / 64) * 64;

  char* p = (char*)d_ws;
  auto alloc = [&](size_t bytes) { void* r = (void*)p; p += (bytes + 255) & ~(size_t)255; return r; };
  float*          xr   = (float*)alloc((size_t)N * D * 4);
  unsigned short* g    = (unsigned short*)alloc((size_t)Npad * NB * D * 2);
  unsigned short* BT0  = (unsigned short*)alloc((size_t)D * NB * D * 2);
  unsigned short* BT1  = (unsigned short*)alloc((size_t)D * NB * D * 2);
  float*          bv0  = (float*)alloc((size_t)NB * D * 4);
  float*          bv1  = (float*)alloc((size_t)NB * D * 4);
  float*          ai   = (float*)alloc((size_t)N * 4);
  float*          ajb  = (float*)alloc((size_t)N * 4 * 4);
  int*            deg  = (int*)alloc((size_t)N * 4);
  int*            offs = (int*)alloc((size_t)(N + 1) * 4);
  int*            cur  = (int*)alloc((size_t)N * 4);
  unsigned*       csr  = (unsigned*)alloc((size_t)E * 4);

  const int* srcp = ei;
  const int* dstp = ei + E;

  // CSR by dst
  hipMemsetAsync(deg, 0, (size_t)N * 4, stream);
  hist_kernel<<<(E + 255) / 256, 256, 0, stream>>>(dstp, deg, E);
  scan_kernel<<<1, 1024, 0, stream>>>(deg, offs, cur, N);
  scatter_kernel<<<(E + 255) / 256, 256, 0, stream>>>(srcp, dstp, etype, cur, csr, E);

  // weight prep (both layers)
  bt_kernel<<<(NB * D * D) / 256, 256, 0, stream>>>(basis, BT0);
  bt_kernel<<<(NB * D * D) / 256, 256, 0, stream>>>(basis + (size_t)NB * D * D, BT1);
  bv_kernel<<<1, 512, 0, stream>>>(basis, att, bv0);
  bv_kernel<<<1, 512, 0, stream>>>(basis + (size_t)NB * D * D, att + 2 * D, bv1);

  float* states = out + (size_t)N * D;  // [L, N, D]
  const float* xin = x0;
  const int gblk = (N + 63) / 64;
  for (int l = 0; l < NLAYER; ++l) {
    const unsigned short* BT_l = l ? BT1 : BT0;
    const float* bv_l = l ? bv1 : bv0;
    gemm_xr<<<dim3(gblk, 2), 256, 0, stream>>>(xin, root + (size_t)l * D * D, xr, N);
    a2_kernel<<<N, 128, 0, stream>>>(xin, xr, att + (size_t)l * 2 * D, bv_l, ai, ajb);
    node_flash<<<N, 128, 0, stream>>>(xin, ai, ajb, offs, csr,
                                      att_r + (size_t)l * NR * NB, g);
    float* st = states + (size_t)l * N * D;
    gemm2_kernel<<<gblk, 256, 0, stream>>>(g, BT_l, xr, bias + (size_t)l * D,
                                           lnw + (size_t)l * D, lnb + (size_t)l * D,
                                           st, (l == NLAYER - 1) ? out : nullptr, N);
    xin = st;
  }
}

// Round 3
// 508.191 us; speedup vs baseline: 1.9946x; 1.4208x over previous
//
#include <hip/hip_runtime.h>
#include <math.h>

#define D 128
#define NB 4      // num bases
#define NR 8      // num relations
#define NLAYER 2
#define KTOT 640  // 512 (bases) + 128 (root)
#define EPSV 1e-5f
#define SLOPE 0.2f

typedef __attribute__((ext_vector_type(8))) short short8;   // 8 bf16 = 4 VGPRs
typedef __attribute__((ext_vector_type(4))) float f32x4;

__device__ __forceinline__ unsigned short f2bf(float f) {
  unsigned u = __float_as_uint(f);
  u += 0x7FFF + ((u >> 16) & 1);          // round-to-nearest-even
  return (unsigned short)(u >> 16);
}
__device__ __forceinline__ float bf2f(unsigned short b) {
  return __uint_as_float(((unsigned)b) << 16);
}

// ---------------- block reductions (128 threads = 2 waves) ----------------
__device__ __forceinline__ float block_sum_128(float v, volatile float* scratch) {
#pragma unroll
  for (int off = 32; off > 0; off >>= 1) v += __shfl_xor(v, off);
  __syncthreads();
  if ((threadIdx.x & 63) == 0) scratch[threadIdx.x >> 6] = v;
  __syncthreads();
  return scratch[0] + scratch[1];
}
__device__ __forceinline__ float block_max_128(float v, volatile float* scratch) {
#pragma unroll
  for (int off = 32; off > 0; off >>= 1) v = fmaxf(v, __shfl_xor(v, off));
  __syncthreads();
  if ((threadIdx.x & 63) == 0) scratch[threadIdx.x >> 6] = v;
  __syncthreads();
  return fmaxf(scratch[0], scratch[1]);
}

// ---------------- CSR build ----------------
__global__ void hist_kernel(const int* __restrict__ dst, int* __restrict__ deg, int E) {
  int e = blockIdx.x * 256 + threadIdx.x;
  if (e < E) atomicAdd(&deg[dst[e]], 1);
}

__global__ void __launch_bounds__(1024) scan_kernel(const int* __restrict__ deg,
                                                    int* __restrict__ offs,
                                                    int* __restrict__ cur, int n) {
  __shared__ int wsums[16];
  const int tid = threadIdx.x, lane = tid & 63, wid = tid >> 6;
  int carry = 0;
  for (int base = 0; base < n + 1023; base += 1024) {
    int i = base + tid;
    int v = (i < n) ? deg[i] : 0;
    int x = v;
#pragma unroll
    for (int off = 1; off < 64; off <<= 1) {
      int yv = __shfl_up(x, off);
      if (lane >= off) x += yv;
    }
    if (lane == 63) wsums[wid] = x;
    __syncthreads();
    if (wid == 0) {
      int ws = (lane < 16) ? wsums[lane] : 0;
#pragma unroll
      for (int off = 1; off < 16; off <<= 1) {
        int yv = __shfl_up(ws, off);
        if (lane >= off) ws += yv;
      }
      if (lane < 16) wsums[lane] = ws;
    }
    __syncthreads();
    int prefix = (wid > 0) ? wsums[wid - 1] : 0;
    int excl = carry + prefix + x - v;
    if (i < n) { offs[i] = excl; cur[i] = excl; }
    int btot = wsums[15];
    __syncthreads();
    carry += btot;
  }
  if (tid == 0) offs[n] = carry;
}

__global__ void scatter_kernel(const int* __restrict__ src, const int* __restrict__ dst,
                               const int* __restrict__ et, int* __restrict__ cur,
                               unsigned* __restrict__ csr, int E) {
  int e = blockIdx.x * 256 + threadIdx.x;
  if (e < E) {
    int d = dst[e];
    int pos = atomicAdd(&cur[d], 1);
    csr[pos] = (unsigned)src[e] | ((unsigned)et[e] << 16);
  }
}

// ---------------- weight prep ----------------
// BT[o][k] bf16, o=0..127 output col, k=0..639 (k<512: basis[b=k>>7][i=k&127][o]; else root[k-512][o])
__global__ void bt_kernel(const float* __restrict__ basis_l, const float* __restrict__ root_l,
                          unsigned short* __restrict__ BT) {
  int k = blockIdx.x, o = threadIdx.x;
  float v = (k < 512) ? basis_l[(size_t)(k >> 7) * (D * D) + (size_t)(k & 127) * D + o]
                      : root_l[(size_t)(k - 512) * D + o];
  BT[(size_t)o * KTOT + k] = f2bf(v);
}
// av[k] = sum_o W[k][o]*att2[o] (k<512), = sum_o root[k-512][o]*att1[o] (k>=512)
__global__ void av_kernel(const float* __restrict__ basis_l, const float* __restrict__ root_l,
                          const float* __restrict__ att_l, float* __restrict__ av) {
  int k = blockIdx.x * 128 + threadIdx.x;
  const float* base;
  const float* w;
  if (k < 512) { base = basis_l + (size_t)(k >> 7) * (D * D) + (size_t)(k & 127) * D; w = att_l + D; }
  else         { base = root_l + (size_t)(k - 512) * D;                               w = att_l; }
  float s = 0.f;
#pragma unroll 8
  for (int o = 0; o < D; ++o) s = fmaf(base[o], w[o], s);
  av[k] = s;
}
// xb init: ga[n][512+c] = bf16(x0[n][c]), zero rows >= N
__global__ void prep_x(const float* __restrict__ x0, unsigned short* __restrict__ ga, int N) {
  int n = blockIdx.x, c = threadIdx.x;
  float v = (n < N) ? x0[(size_t)n * D + c] : 0.f;
  ga[(size_t)n * KTOT + 512 + c] = f2bf(v);
}

// ---------------- per-node attention scalars: one wave per node ----------------
__global__ void __launch_bounds__(256) a2_kernel(const unsigned short* __restrict__ ga,
                                                 const float* __restrict__ av,
                                                 float* __restrict__ ai,
                                                 float* __restrict__ ajb, int N) {
  int n = blockIdx.x * 4 + (threadIdx.x >> 6);
  int lane = threadIdx.x & 63;
  if (n >= N) return;
  unsigned xv = *(const unsigned*)(ga + (size_t)n * KTOT + 512 + 2 * lane);
  float x0 = bf2f((unsigned short)(xv & 0xFFFF)), x1 = bf2f((unsigned short)(xv >> 16));
  float d[5];
#pragma unroll
  for (int b = 0; b < 4; ++b) {
    float2 w = *(const float2*)(av + b * D + 2 * lane);
    d[b] = x0 * w.x + x1 * w.y;
  }
  {
    float2 w = *(const float2*)(av + 512 + 2 * lane);
    d[4] = x0 * w.x + x1 * w.y;
  }
#pragma unroll
  for (int off = 1; off < 64; off <<= 1) {
#pragma unroll
    for (int i = 0; i < 5; ++i) d[i] += __shfl_xor(d[i], off);
  }
  if (lane == 0) {
    *(float4*)(ajb + (size_t)n * 4) = make_float4(d[0], d[1], d[2], d[3]);
    ai[n] = d[4];
  }
}

// ---------------- flash softmax + x-space scatter: g[n,b,:] = sum_e alpha*c[et,b]*x[src] ----
__global__ void __launch_bounds__(128) node_flash(
    unsigned short* __restrict__ ga, const float* __restrict__ ai, const float* __restrict__ ajb,
    const int* __restrict__ offs, const unsigned* __restrict__ csr,
    const float* __restrict__ attr_l) {
  __shared__ float s_c[NR * NB];
  __shared__ float s_wc[128][4];
  __shared__ float s_ex[128];
  __shared__ unsigned s_pk[128];
  __shared__ float scratch[2];
  const int n = blockIdx.x, t = threadIdx.x;
  if (t < NR * NB) s_c[t] = attr_l[t];
  const int b0 = offs[n], b1 = offs[n + 1];
  const float ain = ai[n];
  __syncthreads();
  float m = -INFINITY, ssum = 0.f;
  float a0 = 0.f, a1 = 0.f, a2 = 0.f, a3 = 0.f;
  for (int cb = b0; cb < b1; cb += 128) {
    int cnt = min(128, b1 - cb);
    float alpha = -INFINITY;
    unsigned pk = 0, rt = 0;
    if (t < cnt) {
      pk = csr[cb + t];
      unsigned sn = pk & 0xFFFFu; rt = pk >> 16;
      float4 aj = *(const float4*)(ajb + (size_t)sn * 4);
      float a = ain + s_c[rt * 4 + 0] * aj.x + s_c[rt * 4 + 1] * aj.y +
                s_c[rt * 4 + 2] * aj.z + s_c[rt * 4 + 3] * aj.w;
      alpha = a > 0.f ? a : SLOPE * a;
    }
    s_pk[t] = pk;
    float cmax = block_max_128(alpha, scratch);
    float nm = fmaxf(m, cmax);
    float ex = (t < cnt) ? __expf(alpha - nm) : 0.f;
    s_ex[t] = ex;
    s_wc[t][0] = ex * s_c[rt * 4 + 0]; s_wc[t][1] = ex * s_c[rt * 4 + 1];
    s_wc[t][2] = ex * s_c[rt * 4 + 2]; s_wc[t][3] = ex * s_c[rt * 4 + 3];
    float csum = block_sum_128(ex, scratch);   // barrier publishes s_ex/s_pk/s_wc
    float f = __expf(m - nm);                  // first chunk: 0, accs are 0
    ssum = ssum * f + csum;
    a0 *= f; a1 *= f; a2 *= f; a3 *= f;
    m = nm;
    for (int j = 0; j < cnt; ++j) {
      unsigned sn = s_pk[j] & 0xFFFFu;
      float xv = bf2f(ga[(size_t)sn * KTOT + 512 + t]);
      a0 = fmaf(s_wc[j][0], xv, a0);
      a1 = fmaf(s_wc[j][1], xv, a1);
      a2 = fmaf(s_wc[j][2], xv, a2);
      a3 = fmaf(s_wc[j][3], xv, a3);
    }
    __syncthreads();
  }
  float inv = 1.f / (ssum + 1e-16f);
  unsigned short* gp = ga + (size_t)n * KTOT;
  gp[t]           = f2bf(a0 * inv);
  gp[D + t]       = f2bf(a1 * inv);
  gp[2 * D + t]   = f2bf(a2 * inv);
  gp[3 * D + t]   = f2bf(a3 * inv);
}

// ---------------- MFMA GEMM: out = tanh(LN(ga[N,640]@W[640,128] + bias)) ----------------
// 256 thr = 4 waves, 64 rows/block. B staged through LDS in 5 k-chunks of 128.
// A frag: A[m=l15][k=quad*8+j]; B frag: B[k=quad*8+j][n=l15]; C/D: col=l15, row=quad*4+reg.
__global__ void __launch_bounds__(256) gemm2_kernel(
    unsigned short* __restrict__ ga, const unsigned short* __restrict__ BT,
    const float* __restrict__ bias_l, const float* __restrict__ lnw_l,
    const float* __restrict__ lnb_l, float* __restrict__ st,
    float* __restrict__ xfinal, int n_nodes) {
  __shared__ unsigned short sB[128 * 136];     // [col][k] pad->stride 136 (17x8): min-pass b128
  const int tid = threadIdx.x;
  const int wv = tid >> 6, lane = tid & 63;
  const int l15 = lane & 15, quad = lane >> 4;
  const int rowb = blockIdx.x * 64 + wv * 16;
  const unsigned short* garow = ga + (size_t)(rowb + l15) * KTOT;
  f32x4 acc[8];
  const f32x4 zero = {0.f, 0.f, 0.f, 0.f};
#pragma unroll
  for (int ct = 0; ct < 8; ++ct) acc[ct] = zero;
#pragma unroll
  for (int ch = 0; ch < 5; ++ch) {
    const int k0 = ch * 128;
    short8 a[4];
#pragma unroll
    for (int kc = 0; kc < 4; ++kc)
      a[kc] = *(const short8*)(garow + k0 + kc * 32 + quad * 8);
    __syncthreads();                            // sB consumers of prev chunk done
#pragma unroll
    for (int p = 0; p < 8; ++p) {
      int idx = p * 256 + tid;                  // 2048 = 128 cols x 16 k8
      int col = idx >> 4, k8 = idx & 15;
      *(short8*)(sB + col * 136 + k8 * 8) =
          *(const short8*)(BT + (size_t)col * KTOT + k0 + k8 * 8);
    }
    __syncthreads();
#pragma unroll
    for (int kc = 0; kc < 4; ++kc) {
#pragma unroll
      for (int ct = 0; ct < 8; ++ct) {
        const short8* b = (const short8*)(sB + (ct * 16 + l15) * 136 + kc * 32 + quad * 8);
        acc[ct] = __builtin_amdgcn_mfma_f32_16x16x32_bf16(a[kc], *b, acc[ct], 0, 0, 0);
      }
    }
  }
  // epilogue: + bias, LayerNorm over 128 cols, tanh; write st/xfinal fp32 + next-layer xb bf16
  const int r0 = rowb + quad * 4;
  float bia[8], lw[8], lb[8];
#pragma unroll
  for (int ct = 0; ct < 8; ++ct) {
    int col = ct * 16 + l15;
    bia[ct] = bias_l[col]; lw[ct] = lnw_l[col]; lb[ct] = lnb_l[col];
  }
  float vsum[4] = {0.f, 0.f, 0.f, 0.f}, vsq[4] = {0.f, 0.f, 0.f, 0.f};
#pragma unroll
  for (int ct = 0; ct < 8; ++ct) {
#pragma unroll
    for (int r = 0; r < 4; ++r) {
      float v = acc[ct][r] + bia[ct];
      acc[ct][r] = v;
      vsum[r] += v; vsq[r] += v * v;
    }
  }
#pragma unroll
  for (int r = 0; r < 4; ++r) {
#pragma unroll
    for (int off = 1; off < 16; off <<= 1) {
      vsum[r] += __shfl_xor(vsum[r], off);
      vsq[r]  += __shfl_xor(vsq[r], off);
    }
  }
  float mu[4], rs[4];
#pragma unroll
  for (int r = 0; r < 4; ++r) {
    mu[r] = vsum[r] * (1.0f / D);
    float var = vsq[r] * (1.0f / D) - mu[r] * mu[r];
    rs[r] = rsqrtf(var + EPSV);
  }
#pragma unroll
  for (int ct = 0; ct < 8; ++ct) {
#pragma unroll
    for (int r = 0; r < 4; ++r) {
      int row = r0 + r;
      if (row >= n_nodes) continue;
      int col = ct * 16 + l15;
      float nv = (acc[ct][r] - mu[r]) * rs[r] * lw[ct] + lb[ct];
      float val = tanhf(nv);
      st[(size_t)row * D + col] = val;
      if (xfinal) xfinal[(size_t)row * D + col] = val;
      ga[(size_t)row * KTOT + 512 + col] = f2bf(val);   // next-layer xb (own rows, post-read)
    }
  }
}

// ---------------- launch ----------------
extern "C" void kernel_launch(void* const* d_in, const int* in_sizes, int n_in,
                              void* d_out, int out_size, void* d_ws, size_t ws_size,
                              hipStream_t stream) {
  const float* x0    = (const float*)d_in[0];
  const int*   ei    = (const int*)d_in[1];
  const int*   etype = (const int*)d_in[2];
  const float* basis = (const float*)d_in[3];
  const float* att_r = (const float*)d_in[4];
  const float* att   = (const float*)d_in[5];
  const float* root  = (const float*)d_in[6];
  const float* bias  = (const float*)d_in[7];
  const float* lnw   = (const float*)d_in[8];
  const float* lnb   = (const float*)d_in[9];
  float* out = (float*)d_out;
  const int N = in_sizes[0] / D;
  const int E = in_sizes[2];
  const int Npad = ((N + 63) / 64) * 64;

  char* p = (char*)d_ws;
  auto alloc = [&](size_t bytes) { void* r = (void*)p; p += (bytes + 255) & ~(size_t)255; return r; };
  unsigned short* ga   = (unsigned short*)alloc((size_t)Npad * KTOT * 2);  // [g(512) | xb(128)]
  unsigned short* BT0  = (unsigned short*)alloc((size_t)D * KTOT * 2);
  unsigned short* BT1  = (unsigned short*)alloc((size_t)D * KTOT * 2);
  float*          av0  = (float*)alloc((size_t)KTOT * 4);
  float*          av1  = (float*)alloc((size_t)KTOT * 4);
  float*          ai   = (float*)alloc((size_t)N * 4);
  float*          ajb  = (float*)alloc((size_t)N * 4 * 4);
  int*            deg  = (int*)alloc((size_t)N * 4);
  int*            offs = (int*)alloc((size_t)(N + 1) * 4);
  int*            cur  = (int*)alloc((size_t)N * 4);
  unsigned*       csr  = (unsigned*)alloc((size_t)E * 4);

  const int* srcp = ei;
  const int* dstp = ei + E;

  // CSR by dst
  hipMemsetAsync(deg, 0, (size_t)N * 4, stream);
  hist_kernel<<<(E + 255) / 256, 256, 0, stream>>>(dstp, deg, E);
  scan_kernel<<<1, 1024, 0, stream>>>(deg, offs, cur, N);
  scatter_kernel<<<(E + 255) / 256, 256, 0, stream>>>(srcp, dstp, etype, cur, csr, E);

  // weight prep (both layers) + xb init
  const float* basis1 = basis + (size_t)NB * D * D;
  const float* root1  = root + (size_t)D * D;
  bt_kernel<<<KTOT, 128, 0, stream>>>(basis, root, BT0);
  bt_kernel<<<KTOT, 128, 0, stream>>>(basis1, root1, BT1);
  av_kernel<<<KTOT / 128, 128, 0, stream>>>(basis, root, att, av0);
  av_kernel<<<KTOT / 128, 128, 0, stream>>>(basis1, root1, att + 2 * D, av1);
  prep_x<<<Npad, 128, 0, stream>>>(x0, ga, N);

  float* states = out + (size_t)N * D;  // [L, N, D]
  for (int l = 0; l < NLAYER; ++l) {
    const unsigned short* BT_l = l ? BT1 : BT0;
    const float* av_l = l ? av1 : av0;
    a2_kernel<<<(N + 3) / 4, 256, 0, stream>>>(ga, av_l, ai, ajb, N);
    node_flash<<<N, 128, 0, stream>>>(ga, ai, ajb, offs, csr, att_r + (size_t)l * NR * NB);
    float* st = states + (size_t)l * N * D;
    gemm2_kernel<<<Npad / 64, 256, 0, stream>>>(ga, BT_l, bias + (size_t)l * D,
                                                lnw + (size_t)l * D, lnb + (size_t)l * D,
                                                st, (l == NLAYER - 1) ? out : nullptr, N);
  }
}

// Round 4
// 442.583 us; speedup vs baseline: 2.2903x; 1.1482x over previous
//
#include <hip/hip_runtime.h>
#include <math.h>

#define D 128
#define NB 4      // num bases
#define NR 8      // num relations
#define NLAYER 2
#define KTOT 640  // 512 (bases) + 128 (root)
#define EPSV 1e-5f
#define SLOPE 0.2f

typedef __attribute__((ext_vector_type(8))) short short8;   // 8 bf16 = 4 VGPRs
typedef __attribute__((ext_vector_type(4))) float f32x4;

__device__ __forceinline__ unsigned short f2bf(float f) {
  unsigned u = __float_as_uint(f);
  u += 0x7FFF + ((u >> 16) & 1);          // round-to-nearest-even
  return (unsigned short)(u >> 16);
}

// ---------------- block reduction (128 threads = 2 waves) ----------------
__device__ __forceinline__ float block_sum_128(float v, volatile float* scratch) {
#pragma unroll
  for (int off = 32; off > 0; off >>= 1) v += __shfl_xor(v, off);
  __syncthreads();
  if ((threadIdx.x & 63) == 0) scratch[threadIdx.x >> 6] = v;
  __syncthreads();
  return scratch[0] + scratch[1];
}

// ---------------- CSR build ----------------
__global__ void hist_kernel(const int* __restrict__ dst, int* __restrict__ deg, int E) {
  int e = blockIdx.x * 256 + threadIdx.x;
  if (e < E) atomicAdd(&deg[dst[e]], 1);
}

__global__ void __launch_bounds__(1024) scan_kernel(const int* __restrict__ deg,
                                                    int* __restrict__ offs,
                                                    int* __restrict__ cur, int n) {
  __shared__ int wsums[16];
  const int tid = threadIdx.x, lane = tid & 63, wid = tid >> 6;
  int carry = 0;
  for (int base = 0; base < n; base += 4096) {
    int i0 = base + tid * 4;
    int v0 = 0, v1 = 0, v2 = 0, v3 = 0;
    if (i0 + 3 < n) {
      int4 q = *(const int4*)(deg + i0);
      v0 = q.x; v1 = q.y; v2 = q.z; v3 = q.w;
    } else if (i0 < n) {
      v0 = deg[i0];
      if (i0 + 1 < n) v1 = deg[i0 + 1];
      if (i0 + 2 < n) v2 = deg[i0 + 2];
    }
    int tsum = v0 + v1 + v2 + v3;
    int x = tsum;
#pragma unroll
    for (int off = 1; off < 64; off <<= 1) {
      int y = __shfl_up(x, off);
      if (lane >= off) x += y;
    }
    if (lane == 63) wsums[wid] = x;
    __syncthreads();
    if (wid == 0) {
      int ws = (lane < 16) ? wsums[lane] : 0;
#pragma unroll
      for (int off = 1; off < 16; off <<= 1) {
        int y = __shfl_up(ws, off);
        if (lane >= off) ws += y;
      }
      if (lane < 16) wsums[lane] = ws;
    }
    __syncthreads();
    int prefix = carry + ((wid > 0) ? wsums[wid - 1] : 0) + x - tsum;
    int e0 = prefix, e1 = e0 + v0, e2 = e1 + v1, e3 = e2 + v2;
    if (i0 < n)     { offs[i0] = e0;     cur[i0] = e0; }
    if (i0 + 1 < n) { offs[i0 + 1] = e1; cur[i0 + 1] = e1; }
    if (i0 + 2 < n) { offs[i0 + 2] = e2; cur[i0 + 2] = e2; }
    if (i0 + 3 < n) { offs[i0 + 3] = e3; cur[i0 + 3] = e3; }
    int btot = wsums[15];
    __syncthreads();
    carry += btot;
  }
  if (tid == 0) offs[n] = carry;
}

__global__ void scatter_kernel(const int* __restrict__ src, const int* __restrict__ dst,
                               const int* __restrict__ et, int* __restrict__ cur,
                               unsigned* __restrict__ csr, int E) {
  int e = blockIdx.x * 256 + threadIdx.x;
  if (e < E) {
    int d = dst[e];
    int pos = atomicAdd(&cur[d], 1);
    csr[pos] = (unsigned)src[e] | ((unsigned)et[e] << 16);
  }
}

// ---------------- fused weight prep (both layers): BT + av ----------------
// block k in [0, 2*KTOT): layer = k/KTOT, k' = k%KTOT.
// BT[o][k'] = bf16(W[k'][o]); av[k'] = sum_o W[k'][o]*att2[o] (k'<512) / att1[o] (root part)
__global__ void __launch_bounds__(128) prep_w(const float* __restrict__ basis,
                                              const float* __restrict__ root,
                                              const float* __restrict__ att,
                                              unsigned short* __restrict__ BT0,
                                              unsigned short* __restrict__ BT1,
                                              float* __restrict__ av0, float* __restrict__ av1) {
  __shared__ float scratch[2];
  int k = blockIdx.x, l = 0;
  if (k >= KTOT) { k -= KTOT; l = 1; }
  const float* basis_l = basis + (size_t)l * NB * D * D;
  const float* root_l  = root + (size_t)l * D * D;
  const float* att_l   = att + (size_t)l * 2 * D;
  unsigned short* BT = l ? BT1 : BT0;
  float* av = l ? av1 : av0;
  const int o = threadIdx.x;
  float v = (k < 512) ? basis_l[(size_t)(k >> 7) * (D * D) + (size_t)(k & 127) * D + o]
                      : root_l[(size_t)(k - 512) * D + o];
  BT[(size_t)o * KTOT + k] = f2bf(v);
  float w = (k < 512) ? att_l[D + o] : att_l[o];
  float s = block_sum_128(v * w, scratch);
  if (o == 0) av[k] = s;
}

// xb init: ga[n][512+c] = bf16(x0[n][c]), zero rows >= N
__global__ void prep_x(const float* __restrict__ x0, unsigned short* __restrict__ ga, int N) {
  int n = blockIdx.x, c = threadIdx.x;
  float v = (n < N) ? x0[(size_t)n * D + c] : 0.f;
  ga[(size_t)n * KTOT + 512 + c] = f2bf(v);
}

// ---------------- per-node attention scalars: one wave per node ----------------
__global__ void __launch_bounds__(256) a2_kernel(const unsigned short* __restrict__ ga,
                                                 const float* __restrict__ av,
                                                 float* __restrict__ ai,
                                                 float* __restrict__ ajb, int N) {
  int n = blockIdx.x * 4 + (threadIdx.x >> 6);
  int lane = threadIdx.x & 63;
  if (n >= N) return;
  unsigned xv = *(const unsigned*)(ga + (size_t)n * KTOT + 512 + 2 * lane);
  float x0 = __uint_as_float(xv << 16);
  float x1 = __uint_as_float(xv & 0xFFFF0000u);
  float d[5];
#pragma unroll
  for (int b = 0; b < 4; ++b) {
    float2 w = *(const float2*)(av + b * D + 2 * lane);
    d[b] = x0 * w.x + x1 * w.y;
  }
  {
    float2 w = *(const float2*)(av + 512 + 2 * lane);
    d[4] = x0 * w.x + x1 * w.y;
  }
#pragma unroll
  for (int off = 1; off < 64; off <<= 1) {
#pragma unroll
    for (int i = 0; i < 5; ++i) d[i] += __shfl_xor(d[i], off);
  }
  if (lane == 0) {
    *(float4*)(ajb + (size_t)n * 4) = make_float4(d[0], d[1], d[2], d[3]);
    ai[n] = d[4];
  }
}

// ---------------- flash softmax + x-space scatter: ONE WAVE PER NODE, no barriers ----------
// g[n,b,:] = (sum_e alpha*c[et,b]*x[src]) / denom, written bf16 into ga cols 0..511.
__global__ void __launch_bounds__(256) node_flash(
    unsigned short* __restrict__ ga, const float* __restrict__ ai, const float* __restrict__ ajb,
    const int* __restrict__ offs, const unsigned* __restrict__ csr,
    const float* __restrict__ attr_l, int N) {
  __shared__ float s_c[NR * NB];
  __shared__ float4 s_wc[4][64];
  __shared__ unsigned s_pk[4][64];
  const int w = threadIdx.x >> 6, lane = threadIdx.x & 63;
  const int n = blockIdx.x * 4 + w;
  if (lane < NR * NB) s_c[lane] = attr_l[lane];   // all waves write identical values (benign)
  if (n >= N) return;
  const int b0 = offs[n], b1 = offs[n + 1];
  const float ain = ai[n];
  float m = -INFINITY, ssum = 0.f;
  float acc[4][2] = {};
  for (int cb = b0; cb < b1; cb += 64) {
    int cnt = min(64, b1 - cb);
    float alpha = -INFINITY;
    unsigned pk = 0;
    float4 cv = make_float4(0.f, 0.f, 0.f, 0.f);
    if (lane < cnt) {
      pk = csr[cb + lane];
      unsigned sn = pk & 0xFFFFu, rt = pk >> 16;
      float4 aj = *(const float4*)(ajb + (size_t)sn * 4);
      cv = *(const float4*)(&s_c[rt * 4]);        // own wave wrote s_c earlier (program order)
      float a = ain + cv.x * aj.x + cv.y * aj.y + cv.z * aj.z + cv.w * aj.w;
      alpha = a > 0.f ? a : SLOPE * a;
    }
    float cmax = alpha;
#pragma unroll
    for (int off = 32; off > 0; off >>= 1) cmax = fmaxf(cmax, __shfl_xor(cmax, off));
    float nm = fmaxf(m, cmax);
    float ex = (lane < cnt) ? __expf(alpha - nm) : 0.f;
    float csum = ex;
#pragma unroll
    for (int off = 32; off > 0; off >>= 1) csum += __shfl_xor(csum, off);
    float f = __expf(m - nm);                     // first chunk: exp(-inf)=0, accs are 0
    ssum = ssum * f + csum;
#pragma unroll
    for (int b = 0; b < 4; ++b) { acc[b][0] *= f; acc[b][1] *= f; }
    m = nm;
    s_pk[w][lane] = pk;
    s_wc[w][lane] = make_float4(ex * cv.x, ex * cv.y, ex * cv.z, ex * cv.w);
    // wave-private LDS region: same-wave write->read ordering via lgkmcnt (compiler)
#pragma unroll 2
    for (int j = 0; j < cnt; ++j) {
      float4 wc = s_wc[w][j];
      unsigned sn = s_pk[w][j] & 0xFFFFu;
      unsigned xv = *(const unsigned*)(ga + (size_t)sn * KTOT + 512 + 2 * lane);
      float x0 = __uint_as_float(xv << 16);
      float x1 = __uint_as_float(xv & 0xFFFF0000u);
      acc[0][0] = fmaf(wc.x, x0, acc[0][0]); acc[0][1] = fmaf(wc.x, x1, acc[0][1]);
      acc[1][0] = fmaf(wc.y, x0, acc[1][0]); acc[1][1] = fmaf(wc.y, x1, acc[1][1]);
      acc[2][0] = fmaf(wc.z, x0, acc[2][0]); acc[2][1] = fmaf(wc.z, x1, acc[2][1]);
      acc[3][0] = fmaf(wc.w, x0, acc[3][0]); acc[3][1] = fmaf(wc.w, x1, acc[3][1]);
    }
  }
  float inv = 1.f / (ssum + 1e-16f);
  unsigned short* gp = ga + (size_t)n * KTOT;
#pragma unroll
  for (int b = 0; b < 4; ++b) {
    unsigned r = (unsigned)f2bf(acc[b][0] * inv) | ((unsigned)f2bf(acc[b][1] * inv) << 16);
    *(unsigned*)(gp + b * D + 2 * lane) = r;
  }
}

// ---------------- MFMA GEMM: out = tanh(LN(ga[N,640]@W[640,128] + bias)) ----------------
// 256 thr = 4 waves, 64 rows/block. B staged through LDS in 10 k-chunks of 64
// (18.4 KB LDS -> ~6 blocks/CU, 75% occupancy vs 50% at K=128 chunks).
// A frag: A[m=l15][k=quad*8+j]; B frag: B[k=quad*8+j][n=l15]; C/D: col=l15, row=quad*4+reg.
__global__ void __launch_bounds__(256) gemm2_kernel(
    unsigned short* __restrict__ ga, const unsigned short* __restrict__ BT,
    const float* __restrict__ bias_l, const float* __restrict__ lnw_l,
    const float* __restrict__ lnb_l, float* __restrict__ st,
    float* __restrict__ xfinal, int n_nodes) {
  __shared__ unsigned short sB[128 * 72];      // [col][k] stride 72 shorts (144 B)
  const int tid = threadIdx.x;
  const int wv = tid >> 6, lane = tid & 63;
  const int l15 = lane & 15, quad = lane >> 4;
  const int rowb = blockIdx.x * 64 + wv * 16;
  const unsigned short* garow = ga + (size_t)(rowb + l15) * KTOT;
  f32x4 acc[8];
  const f32x4 zero = {0.f, 0.f, 0.f, 0.f};
#pragma unroll
  for (int ct = 0; ct < 8; ++ct) acc[ct] = zero;
#pragma unroll
  for (int ch = 0; ch < 10; ++ch) {
    const int k0 = ch * 64;
    short8 a[2];
#pragma unroll
    for (int kc = 0; kc < 2; ++kc)
      a[kc] = *(const short8*)(garow + k0 + kc * 32 + quad * 8);
    __syncthreads();                            // sB consumers of prev chunk done
#pragma unroll
    for (int p = 0; p < 4; ++p) {
      int idx = p * 256 + tid;                  // 1024 = 128 cols x 8 k8
      int col = idx >> 3, k8 = idx & 7;
      *(short8*)(sB + col * 72 + k8 * 8) =
          *(const short8*)(BT + (size_t)col * KTOT + k0 + k8 * 8);
    }
    __syncthreads();
#pragma unroll
    for (int kc = 0; kc < 2; ++kc) {
#pragma unroll
      for (int ct = 0; ct < 8; ++ct) {
        const short8* b = (const short8*)(sB + (ct * 16 + l15) * 72 + kc * 32 + quad * 8);
        acc[ct] = __builtin_amdgcn_mfma_f32_16x16x32_bf16(a[kc], *b, acc[ct], 0, 0, 0);
      }
    }
  }
  // epilogue: + bias, LayerNorm over 128 cols, tanh; write st/xfinal fp32 + next-layer xb bf16
  const int r0 = rowb + quad * 4;
  float bia[8], lw[8], lb[8];
#pragma unroll
  for (int ct = 0; ct < 8; ++ct) {
    int col = ct * 16 + l15;
    bia[ct] = bias_l[col]; lw[ct] = lnw_l[col]; lb[ct] = lnb_l[col];
  }
  float vsum[4] = {0.f, 0.f, 0.f, 0.f}, vsq[4] = {0.f, 0.f, 0.f, 0.f};
#pragma unroll
  for (int ct = 0; ct < 8; ++ct) {
#pragma unroll
    for (int r = 0; r < 4; ++r) {
      float v = acc[ct][r] + bia[ct];
      acc[ct][r] = v;
      vsum[r] += v; vsq[r] += v * v;
    }
  }
#pragma unroll
  for (int r = 0; r < 4; ++r) {
#pragma unroll
    for (int off = 1; off < 16; off <<= 1) {
      vsum[r] += __shfl_xor(vsum[r], off);
      vsq[r]  += __shfl_xor(vsq[r], off);
    }
  }
  float mu[4], rs[4];
#pragma unroll
  for (int r = 0; r < 4; ++r) {
    mu[r] = vsum[r] * (1.0f / D);
    float var = vsq[r] * (1.0f / D) - mu[r] * mu[r];
    rs[r] = rsqrtf(var + EPSV);
  }
#pragma unroll
  for (int ct = 0; ct < 8; ++ct) {
#pragma unroll
    for (int r = 0; r < 4; ++r) {
      int row = r0 + r;
      if (row >= n_nodes) continue;
      int col = ct * 16 + l15;
      float nv = (acc[ct][r] - mu[r]) * rs[r] * lw[ct] + lb[ct];
      float val = tanhf(nv);
      st[(size_t)row * D + col] = val;
      if (xfinal) xfinal[(size_t)row * D + col] = val;
      ga[(size_t)row * KTOT + 512 + col] = f2bf(val);   // next-layer xb (own rows, post-read)
    }
  }
}

// ---------------- launch ----------------
extern "C" void kernel_launch(void* const* d_in, const int* in_sizes, int n_in,
                              void* d_out, int out_size, void* d_ws, size_t ws_size,
                              hipStream_t stream) {
  const float* x0    = (const float*)d_in[0];
  const int*   ei    = (const int*)d_in[1];
  const int*   etype = (const int*)d_in[2];
  const float* basis = (const float*)d_in[3];
  const float* att_r = (const float*)d_in[4];
  const float* att   = (const float*)d_in[5];
  const float* root  = (const float*)d_in[6];
  const float* bias  = (const float*)d_in[7];
  const float* lnw   = (const float*)d_in[8];
  const float* lnb   = (const float*)d_in[9];
  float* out = (float*)d_out;
  const int N = in_sizes[0] / D;
  const int E = in_sizes[2];
  const int Npad = ((N + 63) / 64) * 64;

  char* p = (char*)d_ws;
  auto alloc = [&](size_t bytes) { void* r = (void*)p; p += (bytes + 255) & ~(size_t)255; return r; };
  unsigned short* ga   = (unsigned short*)alloc((size_t)Npad * KTOT * 2);  // [g(512) | xb(128)]
  unsigned short* BT0  = (unsigned short*)alloc((size_t)D * KTOT * 2);
  unsigned short* BT1  = (unsigned short*)alloc((size_t)D * KTOT * 2);
  float*          av0  = (float*)alloc((size_t)KTOT * 4);
  float*          av1  = (float*)alloc((size_t)KTOT * 4);
  float*          ai   = (float*)alloc((size_t)N * 4);
  float*          ajb  = (float*)alloc((size_t)N * 4 * 4);
  int*            deg  = (int*)alloc((size_t)N * 4);
  int*            offs = (int*)alloc((size_t)(N + 1) * 4);
  int*            cur  = (int*)alloc((size_t)N * 4);
  unsigned*       csr  = (unsigned*)alloc((size_t)E * 4);

  const int* srcp = ei;
  const int* dstp = ei + E;

  // CSR by dst
  hipMemsetAsync(deg, 0, (size_t)N * 4, stream);
  hist_kernel<<<(E + 255) / 256, 256, 0, stream>>>(dstp, deg, E);
  scan_kernel<<<1, 1024, 0, stream>>>(deg, offs, cur, N);
  scatter_kernel<<<(E + 255) / 256, 256, 0, stream>>>(srcp, dstp, etype, cur, csr, E);

  // fused weight prep (both layers) + xb init
  prep_w<<<2 * KTOT, 128, 0, stream>>>(basis, root, att, BT0, BT1, av0, av1);
  prep_x<<<Npad, 128, 0, stream>>>(x0, ga, N);

  float* states = out + (size_t)N * D;  // [L, N, D]
  for (int l = 0; l < NLAYER; ++l) {
    const unsigned short* BT_l = l ? BT1 : BT0;
    const float* av_l = l ? av1 : av0;
    a2_kernel<<<(N + 3) / 4, 256, 0, stream>>>(ga, av_l, ai, ajb, N);
    node_flash<<<(N + 3) / 4, 256, 0, stream>>>(ga, ai, ajb, offs, csr,
                                                att_r + (size_t)l * NR * NB, N);
    float* st = states + (size_t)l * N * D;
    gemm2_kernel<<<Npad / 64, 256, 0, stream>>>(ga, BT_l, bias + (size_t)l * D,
                                                lnw + (size_t)l * D, lnb + (size_t)l * D,
                                                st, (l == NLAYER - 1) ? out : nullptr, N);
  }
}

// Round 5
// 418.301 us; speedup vs baseline: 2.4233x; 1.0580x over previous
//
#include <hip/hip_runtime.h>
#include <math.h>

#define D 128
#define NB 4      // num bases
#define NR 8      // num relations
#define NLAYER 2
#define KTOT 640  // 512 (bases) + 128 (root)
#define EPSV 1e-5f
#define SLOPE 0.2f
#define NBUK 32
#define BSHIFT 11   // bucket = dst >> 11

typedef __attribute__((ext_vector_type(8))) short short8;   // 8 bf16 = 4 VGPRs
typedef __attribute__((ext_vector_type(4))) float f32x4;

__device__ __forceinline__ unsigned short f2bf(float f) {
  unsigned u = __float_as_uint(f);
  u += 0x7FFF + ((u >> 16) & 1);          // round-to-nearest-even
  return (unsigned short)(u >> 16);
}

// ---------------- block reduction (128 threads = 2 waves) ----------------
__device__ __forceinline__ float block_sum_128(float v, volatile float* scratch) {
#pragma unroll
  for (int off = 32; off > 0; off >>= 1) v += __shfl_xor(v, off);
  __syncthreads();
  if ((threadIdx.x & 63) == 0) scratch[threadIdx.x >> 6] = v;
  __syncthreads();
  return scratch[0] + scratch[1];
}

// ---------------- CSR build ----------------
__global__ void hist_kernel(const int* __restrict__ dst, int* __restrict__ deg, int E) {
  int e = blockIdx.x * 256 + threadIdx.x;
  if (e < E) atomicAdd(&deg[dst[e]], 1);
}

// single-block scan of deg -> offs/cur; also inits padded bucket cursors bcur[b*16]=offs[b<<BSHIFT]
__global__ void __launch_bounds__(1024) scan_kernel(const int* __restrict__ deg,
                                                    int* __restrict__ offs,
                                                    int* __restrict__ cur,
                                                    int* __restrict__ bcur, int n) {
  __shared__ int wsums[16];
  const int tid = threadIdx.x, lane = tid & 63, wid = tid >> 6;
  int carry = 0;
  for (int base = 0; base < n; base += 4096) {
    int i0 = base + tid * 4;
    int v0 = 0, v1 = 0, v2 = 0, v3 = 0;
    if (i0 + 3 < n) {
      int4 q = *(const int4*)(deg + i0);
      v0 = q.x; v1 = q.y; v2 = q.z; v3 = q.w;
    } else if (i0 < n) {
      v0 = deg[i0];
      if (i0 + 1 < n) v1 = deg[i0 + 1];
      if (i0 + 2 < n) v2 = deg[i0 + 2];
    }
    int tsum = v0 + v1 + v2 + v3;
    int x = tsum;
#pragma unroll
    for (int off = 1; off < 64; off <<= 1) {
      int y = __shfl_up(x, off);
      if (lane >= off) x += y;
    }
    if (lane == 63) wsums[wid] = x;
    __syncthreads();
    if (wid == 0) {
      int ws = (lane < 16) ? wsums[lane] : 0;
#pragma unroll
      for (int off = 1; off < 16; off <<= 1) {
        int y = __shfl_up(ws, off);
        if (lane >= off) ws += y;
      }
      if (lane < 16) wsums[lane] = ws;
    }
    __syncthreads();
    int prefix = carry + ((wid > 0) ? wsums[wid - 1] : 0) + x - tsum;
    int e0 = prefix, e1 = e0 + v0, e2 = e1 + v1, e3 = e2 + v2;
    if (i0 < n)     { offs[i0] = e0;     cur[i0] = e0; }
    if (i0 + 1 < n) { offs[i0 + 1] = e1; cur[i0 + 1] = e1; }
    if (i0 + 2 < n) { offs[i0 + 2] = e2; cur[i0 + 2] = e2; }
    if (i0 + 3 < n) { offs[i0 + 3] = e3; cur[i0 + 3] = e3; }
    int btot = wsums[15];
    __syncthreads();
    carry += btot;
  }
  if (tid == 0) offs[n] = carry;
  __syncthreads();                       // offs[] visible within this (single) workgroup
  if (tid < NBUK) {
    int idx = tid << BSHIFT;
    bcur[tid * 16] = offs[idx < n ? idx : n];
  }
}

// Pass B: bucket edges by dst>>BSHIFT into ebuf (8B records, ~contiguous runs per bucket)
__global__ void __launch_bounds__(1024) bucket_kernel(
    const int* __restrict__ src, const int* __restrict__ dst, const int* __restrict__ et,
    int* __restrict__ bcur, unsigned long long* __restrict__ ebuf, int E) {
  __shared__ int lcnt[NBUK];
  __shared__ int lbase[NBUK];
  const int tid = threadIdx.x;
  const int e = blockIdx.x * 1024 + tid;
  if (tid < NBUK) lcnt[tid] = 0;
  __syncthreads();
  int d = 0, b = 0, rank = 0;
  unsigned pk = 0;
  bool valid = e < E;
  if (valid) {
    d = dst[e];
    pk = (unsigned)src[e] | ((unsigned)et[e] << 16);
    b = d >> BSHIFT;
    rank = atomicAdd(&lcnt[b], 1);
  }
  __syncthreads();
  if (tid < NBUK && lcnt[tid] > 0) lbase[tid] = atomicAdd(&bcur[tid * 16], lcnt[tid]);
  __syncthreads();
  if (valid) ebuf[lbase[b] + rank] = ((unsigned long long)(unsigned)d << 32) | pk;
}

// Pass C: scatter bucket-sorted records into csr (writes confined to ~130KB regions -> L2-merged)
__global__ void scatter2_kernel(const unsigned long long* __restrict__ ebuf,
                                int* __restrict__ cur, unsigned* __restrict__ csr, int E) {
  int e = blockIdx.x * 256 + threadIdx.x;
  if (e < E) {
    unsigned long long r = ebuf[e];
    int d = (int)(r >> 32);
    int pos = atomicAdd(&cur[d], 1);
    csr[pos] = (unsigned)r;
  }
}

// ---------------- fused weight prep (both layers): BT + av ----------------
__global__ void __launch_bounds__(128) prep_w(const float* __restrict__ basis,
                                              const float* __restrict__ root,
                                              const float* __restrict__ att,
                                              unsigned short* __restrict__ BT0,
                                              unsigned short* __restrict__ BT1,
                                              float* __restrict__ av0, float* __restrict__ av1) {
  __shared__ float scratch[2];
  int k = blockIdx.x, l = 0;
  if (k >= KTOT) { k -= KTOT; l = 1; }
  const float* basis_l = basis + (size_t)l * NB * D * D;
  const float* root_l  = root + (size_t)l * D * D;
  const float* att_l   = att + (size_t)l * 2 * D;
  unsigned short* BT = l ? BT1 : BT0;
  float* av = l ? av1 : av0;
  const int o = threadIdx.x;
  float v = (k < 512) ? basis_l[(size_t)(k >> 7) * (D * D) + (size_t)(k & 127) * D + o]
                      : root_l[(size_t)(k - 512) * D + o];
  BT[(size_t)o * KTOT + k] = f2bf(v);
  float w = (k < 512) ? att_l[D + o] : att_l[o];
  float s = block_sum_128(v * w, scratch);
  if (o == 0) av[k] = s;
}

// ---------------- prep_xa: bf16-cast x into ga xb cols + layer-0 ai/ajb (1 wave/node) ------
__global__ void __launch_bounds__(256) prep_xa(const float* __restrict__ x0,
                                               const float* __restrict__ av,
                                               unsigned short* __restrict__ ga,
                                               float* __restrict__ ai,
                                               float* __restrict__ ajb, int N, int Npad) {
  int n = blockIdx.x * 4 + (threadIdx.x >> 6);
  int lane = threadIdx.x & 63;
  if (n >= Npad) return;
  if (n >= N) {                           // zero-pad row (wave-uniform branch)
    *(unsigned*)(ga + (size_t)n * KTOT + 512 + 2 * lane) = 0;
    return;
  }
  float2 xv = *(const float2*)(x0 + (size_t)n * D + 2 * lane);
  unsigned packed = (unsigned)f2bf(xv.x) | ((unsigned)f2bf(xv.y) << 16);
  *(unsigned*)(ga + (size_t)n * KTOT + 512 + 2 * lane) = packed;
  float d[5];
#pragma unroll
  for (int b = 0; b < 4; ++b) {
    float2 w = *(const float2*)(av + b * D + 2 * lane);
    d[b] = xv.x * w.x + xv.y * w.y;
  }
  {
    float2 w = *(const float2*)(av + 512 + 2 * lane);
    d[4] = xv.x * w.x + xv.y * w.y;
  }
#pragma unroll
  for (int off = 1; off < 64; off <<= 1) {
#pragma unroll
    for (int i = 0; i < 5; ++i) d[i] += __shfl_xor(d[i], off);
  }
  if (lane == 0) {
    *(float4*)(ajb + (size_t)n * 4) = make_float4(d[0], d[1], d[2], d[3]);
    ai[n] = d[4];
  }
}

// ---------------- per-node attention scalars (layer 1): one wave per node ----------------
__global__ void __launch_bounds__(256) a2_kernel(const unsigned short* __restrict__ ga,
                                                 const float* __restrict__ av,
                                                 float* __restrict__ ai,
                                                 float* __restrict__ ajb, int N) {
  int n = blockIdx.x * 4 + (threadIdx.x >> 6);
  int lane = threadIdx.x & 63;
  if (n >= N) return;
  unsigned xv = *(const unsigned*)(ga + (size_t)n * KTOT + 512 + 2 * lane);
  float x0 = __uint_as_float(xv << 16);
  float x1 = __uint_as_float(xv & 0xFFFF0000u);
  float d[5];
#pragma unroll
  for (int b = 0; b < 4; ++b) {
    float2 w = *(const float2*)(av + b * D + 2 * lane);
    d[b] = x0 * w.x + x1 * w.y;
  }
  {
    float2 w = *(const float2*)(av + 512 + 2 * lane);
    d[4] = x0 * w.x + x1 * w.y;
  }
#pragma unroll
  for (int off = 1; off < 64; off <<= 1) {
#pragma unroll
    for (int i = 0; i < 5; ++i) d[i] += __shfl_xor(d[i], off);
  }
  if (lane == 0) {
    *(float4*)(ajb + (size_t)n * 4) = make_float4(d[0], d[1], d[2], d[3]);
    ai[n] = d[4];
  }
}

// ---------------- flash softmax + x-space scatter: ONE WAVE PER NODE, no barriers ----------
__global__ void __launch_bounds__(256) node_flash(
    unsigned short* __restrict__ ga, const float* __restrict__ ai, const float* __restrict__ ajb,
    const int* __restrict__ offs, const unsigned* __restrict__ csr,
    const float* __restrict__ attr_l, int N) {
  __shared__ float s_c[NR * NB];
  __shared__ float4 s_wc[4][64];
  __shared__ unsigned s_pk[4][64];
  const int w = threadIdx.x >> 6, lane = threadIdx.x & 63;
  const int n = blockIdx.x * 4 + w;
  if (lane < NR * NB) s_c[lane] = attr_l[lane];   // all waves write identical values (benign)
  if (n >= N) return;
  const int b0 = offs[n], b1 = offs[n + 1];
  const float ain = ai[n];
  float m = -INFINITY, ssum = 0.f;
  float acc[4][2] = {};
  for (int cb = b0; cb < b1; cb += 64) {
    int cnt = min(64, b1 - cb);
    float alpha = -INFINITY;
    unsigned pk = 0;
    float4 cv = make_float4(0.f, 0.f, 0.f, 0.f);
    if (lane < cnt) {
      pk = csr[cb + lane];
      unsigned sn = pk & 0xFFFFu, rt = pk >> 16;
      float4 aj = *(const float4*)(ajb + (size_t)sn * 4);
      cv = *(const float4*)(&s_c[rt * 4]);        // own wave wrote s_c earlier (program order)
      float a = ain + cv.x * aj.x + cv.y * aj.y + cv.z * aj.z + cv.w * aj.w;
      alpha = a > 0.f ? a : SLOPE * a;
    }
    float cmax = alpha;
#pragma unroll
    for (int off = 32; off > 0; off >>= 1) cmax = fmaxf(cmax, __shfl_xor(cmax, off));
    float nm = fmaxf(m, cmax);
    float ex = (lane < cnt) ? __expf(alpha - nm) : 0.f;
    float csum = ex;
#pragma unroll
    for (int off = 32; off > 0; off >>= 1) csum += __shfl_xor(csum, off);
    float f = __expf(m - nm);                     // first chunk: exp(-inf)=0, accs are 0
    ssum = ssum * f + csum;
#pragma unroll
    for (int b = 0; b < 4; ++b) { acc[b][0] *= f; acc[b][1] *= f; }
    m = nm;
    s_pk[w][lane] = pk;
    s_wc[w][lane] = make_float4(ex * cv.x, ex * cv.y, ex * cv.z, ex * cv.w);
    // wave-private LDS region: same-wave write->read ordering via lgkmcnt (compiler)
#pragma unroll 2
    for (int j = 0; j < cnt; ++j) {
      float4 wc = s_wc[w][j];
      unsigned sn = s_pk[w][j] & 0xFFFFu;
      unsigned xv = *(const unsigned*)(ga + (size_t)sn * KTOT + 512 + 2 * lane);
      float x0 = __uint_as_float(xv << 16);
      float x1 = __uint_as_float(xv & 0xFFFF0000u);
      acc[0][0] = fmaf(wc.x, x0, acc[0][0]); acc[0][1] = fmaf(wc.x, x1, acc[0][1]);
      acc[1][0] = fmaf(wc.y, x0, acc[1][0]); acc[1][1] = fmaf(wc.y, x1, acc[1][1]);
      acc[2][0] = fmaf(wc.z, x0, acc[2][0]); acc[2][1] = fmaf(wc.z, x1, acc[2][1]);
      acc[3][0] = fmaf(wc.w, x0, acc[3][0]); acc[3][1] = fmaf(wc.w, x1, acc[3][1]);
    }
  }
  float inv = 1.f / (ssum + 1e-16f);
  unsigned short* gp = ga + (size_t)n * KTOT;
#pragma unroll
  for (int b = 0; b < 4; ++b) {
    unsigned r = (unsigned)f2bf(acc[b][0] * inv) | ((unsigned)f2bf(acc[b][1] * inv) << 16);
    *(unsigned*)(gp + b * D + 2 * lane) = r;
  }
}

// ---------------- MFMA GEMM: out = tanh(LN(ga[N,640]@W[640,128] + bias)) ----------------
// 512 thr = 8 waves, 128 rows/block: 8 waves share each sB stage (half the staging/barriers
// per row vs 4-wave blocks). B staged in 10 k-chunks of 64 (18.4 KB LDS).
// A frag: A[m=l15][k=quad*8+j]; B frag: B[k=quad*8+j][n=l15]; C/D: col=l15, row=quad*4+reg.
__global__ void __launch_bounds__(512) gemm2_kernel(
    unsigned short* __restrict__ ga, const unsigned short* __restrict__ BT,
    const float* __restrict__ bias_l, const float* __restrict__ lnw_l,
    const float* __restrict__ lnb_l, float* __restrict__ st,
    float* __restrict__ xfinal, int n_nodes) {
  __shared__ unsigned short sB[128 * 72];      // [col][k] stride 72 shorts (144 B)
  const int tid = threadIdx.x;
  const int wv = tid >> 6, lane = tid & 63;
  const int l15 = lane & 15, quad = lane >> 4;
  const int rowb = blockIdx.x * 128 + wv * 16;
  const unsigned short* garow = ga + (size_t)(rowb + l15) * KTOT;
  f32x4 acc[8];
  const f32x4 zero = {0.f, 0.f, 0.f, 0.f};
#pragma unroll
  for (int ct = 0; ct < 8; ++ct) acc[ct] = zero;
#pragma unroll
  for (int ch = 0; ch < 10; ++ch) {
    const int k0 = ch * 64;
    short8 a[2];
#pragma unroll
    for (int kc = 0; kc < 2; ++kc)
      a[kc] = *(const short8*)(garow + k0 + kc * 32 + quad * 8);
    __syncthreads();                            // sB consumers of prev chunk done
#pragma unroll
    for (int p = 0; p < 2; ++p) {
      int idx = p * 512 + tid;                  // 1024 = 128 cols x 8 k8
      int col = idx >> 3, k8 = idx & 7;
      *(short8*)(sB + col * 72 + k8 * 8) =
          *(const short8*)(BT + (size_t)col * KTOT + k0 + k8 * 8);
    }
    __syncthreads();
#pragma unroll
    for (int kc = 0; kc < 2; ++kc) {
#pragma unroll
      for (int ct = 0; ct < 8; ++ct) {
        const short8* b = (const short8*)(sB + (ct * 16 + l15) * 72 + kc * 32 + quad * 8);
        acc[ct] = __builtin_amdgcn_mfma_f32_16x16x32_bf16(a[kc], *b, acc[ct], 0, 0, 0);
      }
    }
  }
  // epilogue: + bias, LayerNorm over 128 cols, tanh; write st/xfinal fp32 + next-layer xb bf16
  const int r0 = rowb + quad * 4;
  float bia[8], lw[8], lb[8];
#pragma unroll
  for (int ct = 0; ct < 8; ++ct) {
    int col = ct * 16 + l15;
    bia[ct] = bias_l[col]; lw[ct] = lnw_l[col]; lb[ct] = lnb_l[col];
  }
  float vsum[4] = {0.f, 0.f, 0.f, 0.f}, vsq[4] = {0.f, 0.f, 0.f, 0.f};
#pragma unroll
  for (int ct = 0; ct < 8; ++ct) {
#pragma unroll
    for (int r = 0; r < 4; ++r) {
      float v = acc[ct][r] + bia[ct];
      acc[ct][r] = v;
      vsum[r] += v; vsq[r] += v * v;
    }
  }
#pragma unroll
  for (int r = 0; r < 4; ++r) {
#pragma unroll
    for (int off = 1; off < 16; off <<= 1) {
      vsum[r] += __shfl_xor(vsum[r], off);
      vsq[r]  += __shfl_xor(vsq[r], off);
    }
  }
  float mu[4], rs[4];
#pragma unroll
  for (int r = 0; r < 4; ++r) {
    mu[r] = vsum[r] * (1.0f / D);
    float var = vsq[r] * (1.0f / D) - mu[r] * mu[r];
    rs[r] = rsqrtf(var + EPSV);
  }
#pragma unroll
  for (int ct = 0; ct < 8; ++ct) {
#pragma unroll
    for (int r = 0; r < 4; ++r) {
      int row = r0 + r;
      if (row >= n_nodes) continue;
      int col = ct * 16 + l15;
      float nv = (acc[ct][r] - mu[r]) * rs[r] * lw[ct] + lb[ct];
      float val = tanhf(nv);
      st[(size_t)row * D + col] = val;
      if (xfinal) xfinal[(size_t)row * D + col] = val;
      ga[(size_t)row * KTOT + 512 + col] = f2bf(val);   // next-layer xb (own rows, post-read)
    }
  }
}

// ---------------- launch ----------------
extern "C" void kernel_launch(void* const* d_in, const int* in_sizes, int n_in,
                              void* d_out, int out_size, void* d_ws, size_t ws_size,
                              hipStream_t stream) {
  const float* x0    = (const float*)d_in[0];
  const int*   ei    = (const int*)d_in[1];
  const int*   etype = (const int*)d_in[2];
  const float* basis = (const float*)d_in[3];
  const float* att_r = (const float*)d_in[4];
  const float* att   = (const float*)d_in[5];
  const float* root  = (const float*)d_in[6];
  const float* bias  = (const float*)d_in[7];
  const float* lnw   = (const float*)d_in[8];
  const float* lnb   = (const float*)d_in[9];
  float* out = (float*)d_out;
  const int N = in_sizes[0] / D;
  const int E = in_sizes[2];
  const int Npad = ((N + 127) / 128) * 128;

  char* p = (char*)d_ws;
  auto alloc = [&](size_t bytes) { void* r = (void*)p; p += (bytes + 255) & ~(size_t)255; return r; };
  unsigned short*     ga   = (unsigned short*)alloc((size_t)Npad * KTOT * 2);  // [g(512) | xb(128)]
  unsigned short*     BT0  = (unsigned short*)alloc((size_t)D * KTOT * 2);
  unsigned short*     BT1  = (unsigned short*)alloc((size_t)D * KTOT * 2);
  float*              av0  = (float*)alloc((size_t)KTOT * 4);
  float*              av1  = (float*)alloc((size_t)KTOT * 4);
  float*              ai   = (float*)alloc((size_t)N * 4);
  float*              ajb  = (float*)alloc((size_t)N * 4 * 4);
  int*                deg  = (int*)alloc((size_t)N * 4);
  int*                offs = (int*)alloc((size_t)(N + 1) * 4);
  int*                cur  = (int*)alloc((size_t)N * 4);
  int*                bcur = (int*)alloc((size_t)NBUK * 16 * 4);
  unsigned*           csr  = (unsigned*)alloc((size_t)E * 4);
  unsigned long long* ebuf = (unsigned long long*)alloc((size_t)E * 8);

  const int* srcp = ei;
  const int* dstp = ei + E;

  // CSR by dst: hist -> scan -> bucket (locality) -> scatter
  hipMemsetAsync(deg, 0, (size_t)N * 4, stream);
  hist_kernel<<<(E + 255) / 256, 256, 0, stream>>>(dstp, deg, E);
  scan_kernel<<<1, 1024, 0, stream>>>(deg, offs, cur, bcur, N);
  bucket_kernel<<<(E + 1023) / 1024, 1024, 0, stream>>>(srcp, dstp, etype, bcur, ebuf, E);
  scatter2_kernel<<<(E + 255) / 256, 256, 0, stream>>>(ebuf, cur, csr, E);

  // fused weight prep (both layers) + xb init with layer-0 attention scalars
  prep_w<<<2 * KTOT, 128, 0, stream>>>(basis, root, att, BT0, BT1, av0, av1);
  prep_xa<<<Npad / 4, 256, 0, stream>>>(x0, av0, ga, ai, ajb, N, Npad);

  float* states = out + (size_t)N * D;  // [L, N, D]
  for (int l = 0; l < NLAYER; ++l) {
    const unsigned short* BT_l = l ? BT1 : BT0;
    if (l > 0)  // layer-0 ai/ajb came from prep_xa
      a2_kernel<<<(N + 3) / 4, 256, 0, stream>>>(ga, av1, ai, ajb, N);
    node_flash<<<(N + 3) / 4, 256, 0, stream>>>(ga, ai, ajb, offs, csr,
                                                att_r + (size_t)l * NR * NB, N);
    float* st = states + (size_t)l * N * D;
    gemm2_kernel<<<Npad / 128, 512, 0, stream>>>(ga, BT_l, bias + (size_t)l * D,
                                                 lnw + (size_t)l * D, lnb + (size_t)l * D,
                                                 st, (l == NLAYER - 1) ? out : nullptr, N);
  }
}